// Round 1
// baseline (626.900 us; speedup 1.0000x reference)
//
#include <hip/hip_runtime.h>
#include <hip/hip_bf16.h>

// Problem constants: B=4, T=2048, C=1024, H=16, D=64
// ws layout (bf16/ushort elements):
//   [0 .. 8388608)            q  [B,H,T,D]
//   [8388608 .. 2*8388608)    k  [B,H,T,D]
//   [2*8388608 .. 3*8388608)  v  [B,H,T,D]
//   [3*8388608 .. 4*8388608)  y  [B*T, C] (attention out, pre-Wout)
// total = 64 MB

using f32x4 = __attribute__((ext_vector_type(4))) float;
using s16x8 = __attribute__((ext_vector_type(8))) short;
using s16x4 = __attribute__((ext_vector_type(4))) short;

#define MFMA16(a, b, c) __builtin_amdgcn_mfma_f32_16x16x32_bf16(a, b, c, 0, 0, 0)

__device__ __forceinline__ unsigned short f2bf(float f) {
    unsigned u = __builtin_bit_cast(unsigned, f);
    u += 0x7fffu + ((u >> 16) & 1u);   // round-to-nearest-even
    return (unsigned short)(u >> 16);
}

// ---------------------------------------------------------------------------
// GEMM: C = A @ B + bias.  64x64 tile, BK=32, 4 waves (2x2), each wave 32x32
// (2x2 fragments of 16x16x32 bf16 MFMA).
// MODE 0: A fp32 (x), scatter outputs to q/k/v [B,H,T,D] bf16
// MODE 1: A bf16 (y), outputs fp32 to d_out
// ---------------------------------------------------------------------------
template <int MODE>
__global__ __launch_bounds__(256) void gemm_k(
    const void* __restrict__ Aptr, const float* __restrict__ Bmat,
    const float* __restrict__ bias, void* __restrict__ Cptr,
    int M, int N, int K)
{
    __shared__ unsigned short As[64][40];  // [m][k], +8 pad
    __shared__ unsigned short Bs[64][40];  // [n][k] (transposed), +8 pad

    const int t    = threadIdx.x;
    const int lane = t & 63;
    const int wave = t >> 6;
    const int wm   = wave >> 1, wn = wave & 1;
    const int g    = lane >> 4, li = lane & 15;
    const int m0   = blockIdx.x * 64, n0 = blockIdx.y * 64;

    f32x4 acc[2][2] = {};

    for (int k0 = 0; k0 < K; k0 += 32) {
        __syncthreads();  // previous iter's fragment reads done before restage
        if (MODE == 0) {
            const float* A = (const float*)Aptr;
            const int r = t >> 3, c = (t & 7) * 4;
#pragma unroll
            for (int rr = 0; rr < 64; rr += 32) {
                f32x4 va = *(const f32x4*)(A + (size_t)(m0 + rr + r) * K + k0 + c);
                s16x4 vs;
                vs[0] = (short)f2bf(va[0]); vs[1] = (short)f2bf(va[1]);
                vs[2] = (short)f2bf(va[2]); vs[3] = (short)f2bf(va[3]);
                *(s16x4*)(&As[rr + r][c]) = vs;
            }
        } else {
            const unsigned short* A = (const unsigned short*)Aptr;
            const int r = t >> 2, c = (t & 3) * 8;
            *(s16x8*)(&As[r][c]) = *(const s16x8*)(A + (size_t)(m0 + r) * K + k0 + c);
        }
        {
            const int kk = t >> 4, n4 = (t & 15) * 4;
#pragma unroll
            for (int kp = 0; kp < 32; kp += 16) {
                f32x4 vb = *(const f32x4*)(Bmat + (size_t)(k0 + kp + kk) * N + n0 + n4);
#pragma unroll
                for (int i = 0; i < 4; ++i) Bs[n4 + i][kp + kk] = f2bf(vb[i]);
            }
        }
        __syncthreads();

        s16x8 af[2], bfr[2];
#pragma unroll
        for (int mi = 0; mi < 2; ++mi)
            af[mi] = *(const s16x8*)(&As[wm * 32 + mi * 16 + li][g * 8]);
#pragma unroll
        for (int ni = 0; ni < 2; ++ni)
            bfr[ni] = *(const s16x8*)(&Bs[wn * 32 + ni * 16 + li][g * 8]);
#pragma unroll
        for (int mi = 0; mi < 2; ++mi)
#pragma unroll
            for (int ni = 0; ni < 2; ++ni)
                acc[mi][ni] = MFMA16(af[mi], bfr[ni], acc[mi][ni]);
    }

    // epilogue: D layout (verified): row = (lane>>4)*4 + r, col = lane&15
#pragma unroll
    for (int mi = 0; mi < 2; ++mi)
#pragma unroll
        for (int ni = 0; ni < 2; ++ni)
#pragma unroll
            for (int r = 0; r < 4; ++r) {
                const int m = m0 + wm * 32 + mi * 16 + g * 4 + r;
                const int n = n0 + wn * 32 + ni * 16 + li;
                const float val = acc[mi][ni][r] + bias[n];
                if (MODE == 0) {
                    unsigned short* qkv = (unsigned short*)Cptr;
                    const int s = n >> 10, h = (n >> 6) & 15, d = n & 63;
                    const int b = m >> 11, tt = m & 2047;
                    qkv[(size_t)s * 8388608 +
                        ((size_t)(b * 16 + h) * 2048 + tt) * 64 + d] = f2bf(val);
                } else {
                    ((float*)Cptr)[(size_t)m * N + n] = val;
                }
            }
}

// ---------------------------------------------------------------------------
// Flash attention, causal. 1 wave (64 threads) per block, 16 q-rows per wave,
// iterate 64-key blocks. q/k/v are [B,H,T,D] bf16 with T=2048, D=64.
// QK^T: A=Q (rows contiguous in d), B[k=d][n=key] = K[key][d] (contiguous in d).
// PV: P -> LDS roundtrip to A layout; V read strided (B[k=key][n=d]).
// ---------------------------------------------------------------------------
__global__ __launch_bounds__(64) void attn_k(
    const unsigned short* __restrict__ qbuf,
    const unsigned short* __restrict__ kbuf,
    const unsigned short* __restrict__ vbuf,
    unsigned short* __restrict__ ybuf)
{
    const int lane = threadIdx.x;
    const int g = lane >> 4, li = lane & 15;
    const int q0 = blockIdx.x * 16;
    const int bh = blockIdx.y;  // b*16 + h

    const unsigned short* qb = qbuf + (size_t)bh * 2048 * 64;
    const unsigned short* kb = kbuf + (size_t)bh * 2048 * 64;
    const unsigned short* vb = vbuf + (size_t)bh * 2048 * 64;

    __shared__ unsigned short p_lds[16][72];  // [q_local][key_local], +8 pad

    s16x8 qf[2];
    qf[0] = *(const s16x8*)(qb + (size_t)(q0 + li) * 64 + g * 8);
    qf[1] = *(const s16x8*)(qb + (size_t)(q0 + li) * 64 + 32 + g * 8);

    f32x4 O[4] = {};
    float mrow[4] = {-1e30f, -1e30f, -1e30f, -1e30f};
    float lrow[4] = {0.f, 0.f, 0.f, 0.f};

    const int kbmax = (q0 + 15) >> 6;
    for (int kbi = 0; kbi <= kbmax; ++kbi) {
        const int kbase = kbi * 64;

        // S = Q K^T * scale, S fragment rows = q_local (l>>4)*4+r, cols = key
        f32x4 sfr[4];
#pragma unroll
        for (int nf = 0; nf < 4; ++nf) {
            const unsigned short* kr = kb + (size_t)(kbase + nf * 16 + li) * 64 + g * 8;
            s16x8 kf0 = *(const s16x8*)(kr);
            s16x8 kf1 = *(const s16x8*)(kr + 32);
            f32x4 a = {};
            a = MFMA16(qf[0], kf0, a);
            a = MFMA16(qf[1], kf1, a);
            sfr[nf] = a;
        }

        const bool need_mask = (kbase + 63 > q0);
#pragma unroll
        for (int r = 0; r < 4; ++r) {
            const int row = q0 + g * 4 + r;
            float mx = -1e30f;
#pragma unroll
            for (int nf = 0; nf < 4; ++nf) {
                float v = sfr[nf][r] * 0.125f;  // 1/sqrt(64)
                if (need_mask && (kbase + nf * 16 + li > row)) v = -1e30f;
                sfr[nf][r] = v;
                mx = fmaxf(mx, v);
            }
            mx = fmaxf(mx, __shfl_xor(mx, 1));
            mx = fmaxf(mx, __shfl_xor(mx, 2));
            mx = fmaxf(mx, __shfl_xor(mx, 4));
            mx = fmaxf(mx, __shfl_xor(mx, 8));

            const float mnew = fmaxf(mrow[r], mx);
            const float fac  = __expf(mrow[r] - mnew);
            mrow[r] = mnew;

            float rs = 0.f;
#pragma unroll
            for (int nf = 0; nf < 4; ++nf) {
                float p = __expf(sfr[nf][r] - mnew);
                sfr[nf][r] = p;
                rs += p;
            }
            rs += __shfl_xor(rs, 1);
            rs += __shfl_xor(rs, 2);
            rs += __shfl_xor(rs, 4);
            rs += __shfl_xor(rs, 8);
            lrow[r] = lrow[r] * fac + rs;

#pragma unroll
            for (int nf = 0; nf < 4; ++nf) {
                O[nf][r] *= fac;
                p_lds[g * 4 + r][nf * 16 + li] = f2bf(sfr[nf][r]);
            }
        }

        // P fragments (A layout: row = li, k = key_local)
        s16x8 pf0 = *(const s16x8*)(&p_lds[li][g * 8]);
        s16x8 pf1 = *(const s16x8*)(&p_lds[li][32 + g * 8]);

        // PV: B[k=key][n=d] = V[key][d] -> strided scalar loads (L2-resident)
#pragma unroll
        for (int nf = 0; nf < 4; ++nf) {
            s16x8 vf0, vf1;
#pragma unroll
            for (int j = 0; j < 8; ++j) {
                vf0[j] = (short)vb[(size_t)(kbase + g * 8 + j) * 64 + nf * 16 + li];
                vf1[j] = (short)vb[(size_t)(kbase + 32 + g * 8 + j) * 64 + nf * 16 + li];
            }
            O[nf] = MFMA16(pf0, vf0, O[nf]);
            O[nf] = MFMA16(pf1, vf1, O[nf]);
        }
    }

    const int b = bh >> 4, h = bh & 15;
#pragma unroll
    for (int nf = 0; nf < 4; ++nf)
#pragma unroll
        for (int r = 0; r < 4; ++r) {
            const int row = q0 + g * 4 + r;
            const int d = nf * 16 + li;
            ybuf[((size_t)(b * 2048 + row)) * 1024 + h * 64 + d] =
                f2bf(O[nf][r] / lrow[r]);
        }
}

extern "C" void kernel_launch(void* const* d_in, const int* in_sizes, int n_in,
                              void* d_out, int out_size, void* d_ws, size_t ws_size,
                              hipStream_t stream)
{
    const float* x    = (const float*)d_in[0];
    const float* Wqkv = (const float*)d_in[1];
    const float* bqkv = (const float*)d_in[2];
    const float* Wout = (const float*)d_in[3];
    const float* bout = (const float*)d_in[4];

    unsigned short* qkv  = (unsigned short*)d_ws;            // q,k,v: 3 * 8388608
    unsigned short* ybuf = qkv + (size_t)3 * 8388608;        // y: 8388608

    // 1) qkv = x @ Wqkv + bqkv -> q/k/v [B,H,T,D] bf16
    gemm_k<0><<<dim3(8192 / 64, 3072 / 64), 256, 0, stream>>>(
        (const void*)x, Wqkv, bqkv, (void*)qkv, 8192, 3072, 1024);

    // 2) flash attention -> y [B*T, C] bf16
    attn_k<<<dim3(2048 / 16, 4 * 16), 64, 0, stream>>>(
        qkv, qkv + 8388608, qkv + (size_t)2 * 8388608, ybuf);

    // 3) out = y @ Wout + bout (fp32)
    gemm_k<1><<<dim3(8192 / 64, 1024 / 64), 256, 0, stream>>>(
        (const void*)ybuf, Wout, bout, d_out, 8192, 1024, 1024);
}

// Round 2
// 336.307 us; speedup vs baseline: 1.8641x; 1.8641x over previous
//
#include <hip/hip_runtime.h>
#include <hip/hip_bf16.h>

// B=4, T=2048, C=1024, H=16, D=64
//
// ws (ushort elems), 67.1MB total (same footprint as round 1, proven safe):
//   ws0 [0..8388608)         q [B,H,T,D]     -> after attn: WoutT [1024][1024]
//   ws1 [8388608..16777216)  k [B,H,T,D]
//   ws2 [16777216..25165824) vT [B,H,D,T]
//   ws3 [25165824..33554432) v [B,H,T,D] -> y [B*T,C]
// d_out used as scratch early (dead before final GEMM):
//   xbf   = (ushort*)d_out + 0        [8192][1024] bf16
//   WqkvT = (ushort*)d_out + 8388608  [3072][1024] bf16

using f32x4 = __attribute__((ext_vector_type(4))) float;
using s16x8 = __attribute__((ext_vector_type(8))) short;
using s16x4 = __attribute__((ext_vector_type(4))) short;

#define MFMA16(a, b, c) __builtin_amdgcn_mfma_f32_16x16x32_bf16(a, b, c, 0, 0, 0)

__device__ __forceinline__ unsigned short f2bf(float f) {
    unsigned u = __builtin_bit_cast(unsigned, f);
    u += 0x7fffu + ((u >> 16) & 1u);
    return (unsigned short)(u >> 16);
}

__device__ __forceinline__ void gl_lds16(const void* g, void* l) {
    __builtin_amdgcn_global_load_lds(
        (const __attribute__((address_space(1))) void*)g,
        (__attribute__((address_space(3))) void*)l, 16, 0, 0);
}

// ---------------------------------------------------------------------------
// x fp32 -> bf16, vectorized
// ---------------------------------------------------------------------------
__global__ __launch_bounds__(256) void cvt_x(const float* __restrict__ x,
                                             unsigned short* __restrict__ xb, int n4) {
    int i = blockIdx.x * 256 + threadIdx.x;
    if (i < n4) {
        f32x4 v = ((const f32x4*)x)[i];
        s16x4 o;
        o[0] = (short)f2bf(v[0]); o[1] = (short)f2bf(v[1]);
        o[2] = (short)f2bf(v[2]); o[3] = (short)f2bf(v[3]);
        ((s16x4*)xb)[i] = o;
    }
}

// ---------------------------------------------------------------------------
// W [R][Cc] fp32 -> Wt [Cc][R] bf16 (transpose+convert), 64x64 LDS tiles
// ---------------------------------------------------------------------------
__global__ __launch_bounds__(256) void cvt_tr(const float* __restrict__ W,
                                              unsigned short* __restrict__ Wt,
                                              int R, int Cc) {
    __shared__ unsigned short tile[64][72];
    const int r0 = blockIdx.x * 64, c0 = blockIdx.y * 64;
    const int tid = threadIdx.x;
    const int r = tid >> 4, c4 = (tid & 15) * 4;
#pragma unroll
    for (int i = 0; i < 4; ++i) {
        f32x4 v = *(const f32x4*)(W + (size_t)(r0 + r + i * 16) * Cc + c0 + c4);
#pragma unroll
        for (int j = 0; j < 4; ++j) tile[r + i * 16][c4 + j] = f2bf(v[j]);
    }
    __syncthreads();
#pragma unroll
    for (int i = 0; i < 4; ++i) {
        s16x4 o;
#pragma unroll
        for (int j = 0; j < 4; ++j) o[j] = (short)tile[c4 + j][r + i * 16];
        *(s16x4*)(Wt + (size_t)(c0 + r + i * 16) * R + r0 + c4) = o;
    }
}

// ---------------------------------------------------------------------------
// v [B,H,T,D] -> vT [B,H,D,T] bf16, 64x64 tiles
// ---------------------------------------------------------------------------
__global__ __launch_bounds__(256) void tr_v(const unsigned short* __restrict__ v,
                                            unsigned short* __restrict__ vt) {
    __shared__ unsigned short tile[64][72];
    const int t0 = blockIdx.x * 64;
    const int bh = blockIdx.y;
    const unsigned short* src = v + (size_t)bh * 131072;
    unsigned short* dst = vt + (size_t)bh * 131072;
    const int tid = threadIdx.x;
    const int r = tid >> 3, c = (tid & 7) * 8;
#pragma unroll
    for (int i = 0; i < 2; ++i)
        *(s16x8*)(&tile[r + i * 32][c]) =
            *(const s16x8*)(src + (size_t)(t0 + r + i * 32) * 64 + c);
    __syncthreads();
#pragma unroll
    for (int i = 0; i < 2; ++i) {
        s16x8 o;
#pragma unroll
        for (int j = 0; j < 8; ++j) o[j] = (short)tile[c + j][r + i * 32];
        *(s16x8*)(dst + (size_t)(r + i * 32) * 2048 + t0 + c) = o;
    }
}

// ---------------------------------------------------------------------------
// GEMM (m97 structure): C = A @ Bt^T + bias. A [M][K] bf16, Bt [N][K] bf16.
// 128x128 tile, BK=32, 4 waves (2x2), 4x4 fragments/wave, global_load_lds.
// MODE 0: scatter bf16 to q/k/v [B,H,T,D];  MODE 1: fp32 to outp [M][N].
// ---------------------------------------------------------------------------
template <int MODE>
__global__ __launch_bounds__(256) void gemm_bt(
    const unsigned short* __restrict__ A, const unsigned short* __restrict__ Bt,
    const float* __restrict__ bias,
    unsigned short* __restrict__ qp, unsigned short* __restrict__ kp,
    unsigned short* __restrict__ vp, float* __restrict__ outp,
    int M, int N, int K)
{
    __shared__ unsigned short As[128 * 32];
    __shared__ unsigned short Bs[128 * 32];
    const int tid  = threadIdx.x;
    const int lane = tid & 63, w = tid >> 6;
    const int wm = w >> 1, wn = w & 1;
    const int g = lane >> 4, li = lane & 15;
    const int m0 = blockIdx.x * 128, n0 = blockIdx.y * 128;
    const int srow = lane >> 2, sc = (lane & 3) * 8;  // 16 rows x 4 chunks per issue

    f32x4 acc[4][4] = {};

    for (int k0 = 0; k0 < K; k0 += 32) {
        __syncthreads();
#pragma unroll
        for (int j = 0; j < 2; ++j) {
            const int rr = w * 32 + j * 16;
            gl_lds16(A  + (size_t)(m0 + rr + srow) * K + k0 + sc, As + rr * 32);
            gl_lds16(Bt + (size_t)(n0 + rr + srow) * K + k0 + sc, Bs + rr * 32);
        }
        __syncthreads();

        s16x8 af[4], bf[4];
#pragma unroll
        for (int i = 0; i < 4; ++i)
            af[i] = *(const s16x8*)(As + (wm * 64 + i * 16 + li) * 32 + g * 8);
#pragma unroll
        for (int i = 0; i < 4; ++i)
            bf[i] = *(const s16x8*)(Bs + (wn * 64 + i * 16 + li) * 32 + g * 8);
#pragma unroll
        for (int mi = 0; mi < 4; ++mi)
#pragma unroll
            for (int ni = 0; ni < 4; ++ni)
                acc[mi][ni] = MFMA16(af[mi], bf[ni], acc[mi][ni]);
    }

#pragma unroll
    for (int mi = 0; mi < 4; ++mi)
#pragma unroll
        for (int ni = 0; ni < 4; ++ni)
#pragma unroll
            for (int r = 0; r < 4; ++r) {
                const int m = m0 + wm * 64 + mi * 16 + g * 4 + r;
                const int n = n0 + wn * 64 + ni * 16 + li;
                const float val = acc[mi][ni][r] + bias[n];
                if (MODE == 0) {
                    const int s = n >> 10, h = (n >> 6) & 15, d = n & 63;
                    const int b = m >> 11, tt = m & 2047;
                    unsigned short* dst = (s == 0) ? qp : (s == 1) ? kp : vp;
                    dst[((size_t)(b * 16 + h) * 2048 + tt) * 64 + d] = f2bf(val);
                } else {
                    outp[(size_t)m * N + n] = val;
                }
            }
}

// ---------------------------------------------------------------------------
// Flash attention, causal. 256 threads = 4 waves; block = 64 q-rows
// (wave w: rows q0+16w..+15). Per 64-key block: K and vT staged in LDS via
// global_load_lds with XOR-swizzled source (rule #21), fragments read with
// matching swizzled ds_read_b128 -> conflict-free.
// ---------------------------------------------------------------------------
__global__ __launch_bounds__(256) void attn_k(
    const unsigned short* __restrict__ qbuf,
    const unsigned short* __restrict__ kbuf,
    const unsigned short* __restrict__ vtbuf,
    unsigned short* __restrict__ ybuf)
{
    __shared__ unsigned short Ks[64 * 64];
    __shared__ unsigned short Vs[64 * 64];
    __shared__ unsigned short Ps[4][16][72];

    const int tid  = threadIdx.x;
    const int lane = tid & 63, w = tid >> 6;
    const int g = lane >> 4, li = lane & 15;
    const int q0  = blockIdx.x * 64;
    const int bh  = blockIdx.y;
    const int wq0 = q0 + w * 16;
    const int srow = lane >> 3, schunk = lane & 7;

    const unsigned short* qb  = qbuf  + (size_t)bh * 131072;
    const unsigned short* kb  = kbuf  + (size_t)bh * 131072;
    const unsigned short* vtb = vtbuf + (size_t)bh * 131072;

    s16x8 qf[2];
    qf[0] = *(const s16x8*)(qb + (size_t)(wq0 + li) * 64 + g * 8);
    qf[1] = *(const s16x8*)(qb + (size_t)(wq0 + li) * 64 + 32 + g * 8);

    f32x4 O[4] = {};
    float mrow[4] = {-1e30f, -1e30f, -1e30f, -1e30f};
    float lrow[4] = {0.f, 0.f, 0.f, 0.f};

    const int nkb = blockIdx.x + 1;  // (q0+63)/64 + 1
    for (int kbi = 0; kbi < nkb; ++kbi) {
        const int kbase = kbi * 64;
        __syncthreads();  // prev iter's LDS reads done
#pragma unroll
        for (int j = 0; j < 2; ++j) {
            const int row = w * 16 + j * 8 + srow;          // K row (key) / vT row (d)
            const int csrc = (schunk ^ (row & 7)) * 8;       // pre-swizzled source chunk
            gl_lds16(kb  + (size_t)(kbase + row) * 64 + csrc, Ks + (w * 16 + j * 8) * 64);
            gl_lds16(vtb + (size_t)row * 2048 + kbase + csrc, Vs + (w * 16 + j * 8) * 64);
        }
        __syncthreads();  // staged data visible (compiler drains vmcnt)

        // S = Q K^T
        f32x4 sfr[4];
#pragma unroll
        for (int nf = 0; nf < 4; ++nf) {
            const int key = nf * 16 + li;
            const char* ka = (const char*)Ks + key * 128;
            const int sw = (key & 7) << 4;
            s16x8 kf0 = *(const s16x8*)(ka + ((g * 16) ^ sw));
            s16x8 kf1 = *(const s16x8*)(ka + ((64 + g * 16) ^ sw));
            f32x4 a = {};
            a = MFMA16(qf[0], kf0, a);
            a = MFMA16(qf[1], kf1, a);
            sfr[nf] = a;
        }

        const bool need_mask = (kbase + 63 > wq0);
#pragma unroll
        for (int r = 0; r < 4; ++r) {
            const int row = wq0 + g * 4 + r;
            float mx = -1e30f;
#pragma unroll
            for (int nf = 0; nf < 4; ++nf) {
                float v = sfr[nf][r] * 0.125f;  // 1/sqrt(64)
                if (need_mask && (kbase + nf * 16 + li > row)) v = -1e30f;
                sfr[nf][r] = v;
                mx = fmaxf(mx, v);
            }
            mx = fmaxf(mx, __shfl_xor(mx, 1));
            mx = fmaxf(mx, __shfl_xor(mx, 2));
            mx = fmaxf(mx, __shfl_xor(mx, 4));
            mx = fmaxf(mx, __shfl_xor(mx, 8));

            const float mnew = fmaxf(mrow[r], mx);
            const float fac  = __expf(mrow[r] - mnew);
            mrow[r] = mnew;

            float rs = 0.f;
#pragma unroll
            for (int nf = 0; nf < 4; ++nf) {
                float p = __expf(sfr[nf][r] - mnew);
                sfr[nf][r] = p;
                rs += p;
            }
            rs += __shfl_xor(rs, 1);
            rs += __shfl_xor(rs, 2);
            rs += __shfl_xor(rs, 4);
            rs += __shfl_xor(rs, 8);
            lrow[r] = lrow[r] * fac + rs;

#pragma unroll
            for (int nf = 0; nf < 4; ++nf) {
                O[nf][r] *= fac;
                Ps[w][g * 4 + r][nf * 16 + li] = f2bf(sfr[nf][r]);
            }
        }

        // PV
        s16x8 pf0 = *(const s16x8*)(&Ps[w][li][g * 8]);
        s16x8 pf1 = *(const s16x8*)(&Ps[w][li][32 + g * 8]);
#pragma unroll
        for (int nf = 0; nf < 4; ++nf) {
            const int d = nf * 16 + li;
            const char* va = (const char*)Vs + d * 128;
            const int sw = (d & 7) << 4;
            s16x8 vf0 = *(const s16x8*)(va + ((g * 16) ^ sw));
            s16x8 vf1 = *(const s16x8*)(va + ((64 + g * 16) ^ sw));
            O[nf] = MFMA16(pf0, vf0, O[nf]);
            O[nf] = MFMA16(pf1, vf1, O[nf]);
        }
    }

    const int b = bh >> 4, h = bh & 15;
#pragma unroll
    for (int nf = 0; nf < 4; ++nf)
#pragma unroll
        for (int r = 0; r < 4; ++r) {
            const int row = wq0 + g * 4 + r;
            const int d = nf * 16 + li;
            ybuf[((size_t)(b * 2048 + row)) * 1024 + h * 64 + d] =
                f2bf(O[nf][r] / lrow[r]);
        }
}

extern "C" void kernel_launch(void* const* d_in, const int* in_sizes, int n_in,
                              void* d_out, int out_size, void* d_ws, size_t ws_size,
                              hipStream_t stream)
{
    const float* x    = (const float*)d_in[0];
    const float* Wqkv = (const float*)d_in[1];
    const float* bqkv = (const float*)d_in[2];
    const float* Wout = (const float*)d_in[3];
    const float* bout = (const float*)d_in[4];

    unsigned short* ws0 = (unsigned short*)d_ws;               // q -> WoutT
    unsigned short* ws1 = ws0 + (size_t)8388608;               // k
    unsigned short* ws2 = ws0 + (size_t)2 * 8388608;           // vT
    unsigned short* ws3 = ws0 + (size_t)3 * 8388608;           // v -> y

    unsigned short* xbf   = (unsigned short*)d_out;            // scratch in d_out
    unsigned short* WqkvT = xbf + (size_t)8388608;

    // 1) convert x -> bf16 (into d_out scratch)
    cvt_x<<<8192, 256, 0, stream>>>(x, xbf, 2097152);
    // 2) Wqkv [1024][3072] -> WqkvT [3072][1024] bf16 (into d_out scratch)
    cvt_tr<<<dim3(16, 48), 256, 0, stream>>>(Wqkv, WqkvT, 1024, 3072);
    // 3) qkv GEMM -> q(ws0), k(ws1), v(ws3)
    gemm_bt<0><<<dim3(64, 24), 256, 0, stream>>>(
        xbf, WqkvT, bqkv, ws0, ws1, ws3, nullptr, 8192, 3072, 1024);
    // 4) v -> vT (ws2)
    tr_v<<<dim3(32, 64), 256, 0, stream>>>(ws3, ws2);
    // 5) attention: q,k,vT -> y (ws3, overwrites dead v)
    attn_k<<<dim3(32, 64), 256, 0, stream>>>(ws0, ws1, ws2, ws3);
    // 6) Wout -> WoutT bf16 into ws0 (q dead after attention)
    cvt_tr<<<dim3(16, 16), 256, 0, stream>>>(Wout, ws0, 1024, 1024);
    // 7) out GEMM: y @ WoutT^T + bout -> d_out fp32 (scratch there is dead)
    gemm_bt<1><<<dim3(64, 8), 256, 0, stream>>>(
        ws3, ws0, bout, nullptr, nullptr, nullptr, (float*)d_out, 8192, 1024, 1024);
}